// Round 8
// baseline (400.629 us; speedup 1.0000x reference)
//
#include <hip/hip_runtime.h>
#include <hip/hip_bf16.h>

// Problem constants
constexpr int Bc = 32, Sc = 4096, Dc = 64, Pc = 8, STRIDEc = 4, Hc = 512;
constexpr int Tc = (Sc - Pc) / STRIDEc + 1;   // 1023
constexpr int Kc = Pc * Dc;                   // 512
constexpr float EPSc = 1e-6f;
constexpr int PITCH = 40;                     // bf16 LDS row pitch (80B -> 2-way banks = free)

typedef __bf16 bf16x8 __attribute__((ext_vector_type(8)));
typedef unsigned short ushort8 __attribute__((ext_vector_type(8)));
typedef float f32x4 __attribute__((ext_vector_type(4)));

__device__ __forceinline__ int n_tok_of(int len) {
    return (len >= Pc) ? ((len - Pc) / STRIDEc + 1) : 1;
}

// fp32 -> bf16 round-to-nearest-even
__device__ __forceinline__ unsigned short f2bf(float f) {
    unsigned u = __builtin_bit_cast(unsigned, f);
    u = (u + 0x7FFFu + ((u >> 16) & 1u)) >> 16;
    return (unsigned short)u;
}

// ---------------------------------------------------------------------------
// Prep: Wt_s[k0/32][n][k%32] = bf16(W[k][n])  (transposed, k-slice-packed so
// each k-step's B tile is one contiguous 32 KB block), + token_lengths.
// grid (16,16) tiles of 32x32, 256 threads.  (unchanged from r4)
// ---------------------------------------------------------------------------
__global__ __launch_bounds__(256) void prep_kernel(
        const float* __restrict__ W, const int* __restrict__ lengths,
        unsigned short* __restrict__ Wt, float* __restrict__ out_tl) {
    __shared__ float tile[32][33];
    const int k0 = blockIdx.x * 32, n0 = blockIdx.y * 32;
    const int r = threadIdx.x >> 3, c = (threadIdx.x & 7) * 4;
    const float4 v = *(const float4*)(W + (size_t)(k0 + r) * Hc + n0 + c);
    tile[c + 0][r] = v.x;
    tile[c + 1][r] = v.y;
    tile[c + 2][r] = v.z;
    tile[c + 3][r] = v.w;
    __syncthreads();
    ushort4 o;
    o.x = f2bf(tile[r][c + 0]);
    o.y = f2bf(tile[r][c + 1]);
    o.z = f2bf(tile[r][c + 2]);
    o.w = f2bf(tile[r][c + 3]);
    // slice = blockIdx.x; within slice: n-major, 32 k's per row
    *(ushort4*)(Wt + (size_t)blockIdx.x * (Hc * 32) + (size_t)(n0 + r) * 32 + c) = o;
    if (blockIdx.x == 0 && blockIdx.y == 0 && threadIdx.x < Bc)
        out_tl[threadIdx.x] = (float)n_tok_of(lengths[threadIdx.x]);
}

// ---------------------------------------------------------------------------
// Fused, role-split at block granularity (single launch, 1024 blocks):
//   id <  512: GEMM-only tile (bx=id>>5 ascending => heavy tiles dispatched
//              first). r4's EXACT staged loop minus the token stores;
//              epilogue writes hidden rows t < ntok only. Light tiles
//              (t0 >= ntok) return instantly => HW dispatcher backfills
//              their CU slots with stream blocks (dynamic balancing without
//              atomics/persistent loops).
//   id >= 512: stream tile: tokens rows (copy x / zeros) + hidden rows
//              t >= ntok (= cvec), dense per-row nontemporal bursts.
// Output partition is exact: GEMM writes hidden[t<ntok]; stream writes
// hidden[t>=ntok] and ALL tokens. No overlapping writes.
// ---------------------------------------------------------------------------
__global__ __launch_bounds__(256, 2) void fused_kernel(
        const float* __restrict__ x, const int* __restrict__ lengths,
        const unsigned short* __restrict__ Wt, const float* __restrict__ bias,
        const float* __restrict__ scale, float* __restrict__ hidden,
        float* __restrict__ tokens) {
    const int id  = (int)blockIdx.x;
    const int tid = threadIdx.x;

    if (id >= 512) {
        // ================= stream tile =================
        const int sid = id - 512;
        const int b   = sid & 31;
        const int t0  = (sid >> 5) * 64;
        const int ntok = n_tok_of(lengths[b]);

        // cvec = scale * bias * rsqrt(mean(bias^2)+eps)   (uniform)
        __shared__ float red[4];
        const int w = tid >> 6, lane = tid & 63;
        const float2 b2 = *(const float2*)(bias + tid * 2);
        float s = b2.x * b2.x + b2.y * b2.y;
#pragma unroll
        for (int off = 32; off; off >>= 1) s += __shfl_xor(s, off);
        if (lane == 0) red[w] = s;
        __syncthreads();
        const float rstd0 = rsqrtf((red[0] + red[1] + red[2] + red[3])
                                   * (1.0f / (float)Hc) + EPSc);

        // 4 threads per row; each thread streams 512B (128 floats) of its row
        const int r = tid >> 2;                  // row in tile 0..63
        const int q = tid & 3;                   // quarter of the 512-f32 row
        const int t = t0 + r;
        if (t < Tc) {
            float* tokp = tokens + ((size_t)b * Tc + t) * Kc + q * 128;
            if (t < ntok) {
                // valid token row = 512 contiguous floats of x (overlap-gather)
                const float* xs = x + (size_t)b * (Sc * Dc) + (size_t)t * (STRIDEc * Dc)
                                + q * 128;
#pragma unroll
                for (int j = 0; j < 32; ++j) {
                    const f32x4 v = *(const f32x4*)(xs + j * 4);
                    __builtin_nontemporal_store(v, (f32x4*)(tokp + j * 4));
                }
            } else {
                const f32x4 z = {0.f, 0.f, 0.f, 0.f};
#pragma unroll
                for (int j = 0; j < 32; ++j)
                    __builtin_nontemporal_store(z, (f32x4*)(tokp + j * 4));
                float* hidp = hidden + ((size_t)b * Tc + t) * Hc + q * 128;
#pragma unroll
                for (int j = 0; j < 32; ++j) {
                    const int c = q * 128 + j * 4;
                    const f32x4 cv = *(const f32x4*)(bias + c) * rstd0
                                   * *(const f32x4*)(scale + c);
                    __builtin_nontemporal_store(cv, (f32x4*)(hidp + j * 4));
                }
            }
        }
        return;
    }

    // ================= GEMM tile (r4 structure, stores removed) =================
    const int b  = id & 31;
    const int t0 = (id >> 5) * 64;               // bx ascending => heavy first
    const int ntok = n_tok_of(lengths[b]);
    if (t0 >= ntok) return;                      // stream blocks own these rows

    __shared__ unsigned short As[64 * PITCH];    // As[r][k], bf16 (token tile)
    __shared__ unsigned short Bs[512 * PITCH];   // Bs[n][k], bf16 (Wt tile)
    __shared__ float ssbuf[4][64];

    const int w    = tid >> 6;
    const int lane = tid & 63;
    const int l15  = lane & 15;
    const int quad = lane >> 4;

    f32x4 acc[4][8];                             // [ttile][ctile]
#pragma unroll
    for (int tt = 0; tt < 4; ++tt)
#pragma unroll
        for (int ct = 0; ct < 8; ++ct) acc[tt][ct] = (f32x4){0.f, 0.f, 0.f, 0.f};

    const float* xb = x + (size_t)b * (Sc * Dc);

    // Per-thread staging coordinates (A: 2 float4 chunks; B: 8 ushort8 chunks)
    int   a_r[2], a_c[2];  bool a_lv[2];  const float* a_src[2];
#pragma unroll
    for (int it = 0; it < 2; ++it) {
        const int l = tid + it * 256;
        a_r[it] = l >> 3;                        // row in tile (0..63)
        a_c[it] = (l & 7) * 4;                   // k offset within 32-k tile
        const int t = t0 + a_r[it];
        a_lv[it] = (t < ntok);                   // row fully valid iff t < ntok
        a_src[it] = xb + (size_t)t * (STRIDEc * Dc);
    }

    float4  ra[2];
    ushort8 rb[8];

    // ---- prologue loads (k0 = 0) ----
#pragma unroll
    for (int it = 0; it < 2; ++it) {
        ra[it] = make_float4(0.f, 0.f, 0.f, 0.f);
        if (a_lv[it]) ra[it] = *(const float4*)(a_src[it] + a_c[it]);
    }
#pragma unroll
    for (int it = 0; it < 8; ++it)
        rb[it] = *(const ushort8*)(Wt + (size_t)(tid + it * 256) * 8);

    for (int step = 0; step < 16; ++step) {
        if (step) __syncthreads();               // previous MFMA reads done

        // ---- commit staged regs to LDS ----
#pragma unroll
        for (int it = 0; it < 2; ++it) {
            const float4 v = ra[it];
            ushort4 h4;
            h4.x = f2bf(v.x); h4.y = f2bf(v.y); h4.z = f2bf(v.z); h4.w = f2bf(v.w);
            *(ushort4*)(As + a_r[it] * PITCH + a_c[it]) = h4;
        }
#pragma unroll
        for (int it = 0; it < 8; ++it) {
            const int cc = tid + it * 256;
            *(ushort8*)(Bs + (cc >> 2) * PITCH + (cc & 3) * 8) = rb[it];
        }
        __syncthreads();

        // ---- prefetch next tile while MFMA runs ----
        if (step < 15) {
            const int kn = step * 32 + 32;
#pragma unroll
            for (int it = 0; it < 2; ++it) {
                ra[it] = make_float4(0.f, 0.f, 0.f, 0.f);
                if (a_lv[it]) ra[it] = *(const float4*)(a_src[it] + kn + a_c[it]);
            }
            const unsigned short* wsrc = Wt + (size_t)(step + 1) * (Hc * 32);
#pragma unroll
            for (int it = 0; it < 8; ++it)
                rb[it] = *(const ushort8*)(wsrc + (size_t)(tid + it * 256) * 8);
        }

        // ---- MFMA (operand-swapped) ----
        bf16x8 btok[4];
#pragma unroll
        for (int tt = 0; tt < 4; ++tt)
            btok[tt] = __builtin_bit_cast(bf16x8,
                *(const ushort8*)(As + (tt * 16 + l15) * PITCH + quad * 8));
#pragma unroll
        for (int ct = 0; ct < 8; ++ct) {
            bf16x8 aW = __builtin_bit_cast(bf16x8,
                *(const ushort8*)(Bs + (w * 128 + ct * 16 + l15) * PITCH + quad * 8));
#pragma unroll
            for (int tt = 0; tt < 4; ++tt)
                acc[tt][ct] = __builtin_amdgcn_mfma_f32_16x16x32_bf16(
                    aW, btok[tt], acc[tt][ct], 0, 0, 0);
        }
    }

    // ---- epilogue: bias, in-register row sums, RMS, scale ----
    float ss[4] = {0.f, 0.f, 0.f, 0.f};
#pragma unroll
    for (int ct = 0; ct < 8; ++ct) {
        const f32x4 b4 = *(const f32x4*)(bias + w * 128 + ct * 16 + quad * 4);
#pragma unroll
        for (int tt = 0; tt < 4; ++tt) {
            f32x4 h = acc[tt][ct] + b4;
            acc[tt][ct] = h;
            ss[tt] += h[0] * h[0] + h[1] * h[1] + h[2] * h[2] + h[3] * h[3];
        }
    }
#pragma unroll
    for (int tt = 0; tt < 4; ++tt) {
        float s = ss[tt];
        s += __shfl_xor(s, 16);
        s += __shfl_xor(s, 32);
        if (quad == 0) ssbuf[w][tt * 16 + l15] = s;
    }
    __syncthreads();
    float rstd[4];
#pragma unroll
    for (int tt = 0; tt < 4; ++tt) {
        const int r = tt * 16 + l15;
        const float tot = ssbuf[0][r] + ssbuf[1][r] + ssbuf[2][r] + ssbuf[3][r];
        rstd[tt] = rsqrtf(tot * (1.0f / (float)Hc) + EPSc);
    }
    // hidden rows t < ntok only (rows >= ntok are the stream blocks' cvec rows)
#pragma unroll
    for (int ct = 0; ct < 8; ++ct) {
        const f32x4 s4 = *(const f32x4*)(scale + w * 128 + ct * 16 + quad * 4);
#pragma unroll
        for (int tt = 0; tt < 4; ++tt) {
            const int t = t0 + tt * 16 + l15;
            if (t < ntok) {
                f32x4 o = acc[tt][ct] * rstd[tt] * s4;
                *(f32x4*)(hidden + ((size_t)b * Tc + t) * Hc
                          + w * 128 + ct * 16 + quad * 4) = o;
            }
        }
    }
}

extern "C" void kernel_launch(void* const* d_in, const int* in_sizes, int n_in,
                              void* d_out, int out_size, void* d_ws, size_t ws_size,
                              hipStream_t stream) {
    const float* x       = (const float*)d_in[0];
    const int*   lengths = (const int*)d_in[1];
    const float* W       = (const float*)d_in[2];
    const float* bias    = (const float*)d_in[3];
    const float* scale   = (const float*)d_in[4];

    const size_t BTH = (size_t)Bc * Tc * Hc;   // 16,760,832
    float* out    = (float*)d_out;
    float* hidden = out;                        // output 0
    float* tl     = out + BTH;                  // output 1 (32 floats)
    float* tokens = out + BTH + Bc;             // output 2

    unsigned short* Wt = (unsigned short*)d_ws; // 512x512 bf16 = 512 KB, k-slice-packed

    {   // W -> Wt (transpose + bf16 + slice-pack) and token_lengths
        dim3 grid(Hc / 32, Hc / 32);            // (16,16)
        prep_kernel<<<grid, 256, 0, stream>>>(W, lengths, Wt, tl);
    }
    {   // role-split fused kernel: 512 GEMM tiles first, then 512 stream tiles
        fused_kernel<<<dim3(1024), 256, 0, stream>>>(x, lengths, Wt, bias, scale,
                                                     hidden, tokens);
    }
}